// Round 1
// baseline (22506.255 us; speedup 1.0000x reference)
//
#include <hip/hip_runtime.h>
#include <hip/hip_bf16.h>
#include <cstdint>
#include <cstddef>

#define NEc 16
#define SSc 16
#define BBc 256
#define INc 61
#define HHc 1024
#define LLc 512
#define H3c 3072
#define NEBc 4096   // NE*B
#define SNBc 65536  // S*NE*B

__device__ __forceinline__ float sigmoidf_(float x){ return 1.0f/(1.0f+__expf(-x)); }

// C[M,N] = A[M,K] @ B[N,K]^T   (both row-major, K contiguous: "NT" GEMM)
template<int BM,int BN,int BK,int TM,int TN,bool VEC>
__global__ __launch_bounds__(256) void gemm_nt(const float* __restrict__ A, int lda,
                                               const float* __restrict__ B, int ldb,
                                               float* __restrict__ C, int ldc,
                                               int M, int N, int K)
{
    static_assert(BM==BN, "square tiles only");
    constexpr int KV = BK/4;
    static_assert(BM*KV == 256, "one float4 per thread per operand tile");
    constexpr int PAD = 4;
    __shared__ float As[BK][BM+PAD];
    __shared__ float Bs[BK][BN+PAD];
    const int tid  = threadIdx.x;
    const int lane = tid & 63;
    const int wave = tid >> 6;
    // wave-aware mapping: within a wave, 8x8 lane grid -> <=2-way LDS bank alias (free)
    const int ty = ((wave>>1)<<3) + (lane>>3);   // 0..15 (M dir group)
    const int tx = ((wave&1)<<3) + (lane&7);     // 0..15 (N dir group)
    const int m0 = blockIdx.y * BM;
    const int n0 = blockIdx.x * BN;
    const int lrow = tid / KV;
    const int lcol = (tid % KV)*4;

    float acc[TM][TN];
    #pragma unroll
    for (int i=0;i<TM;i++)
      #pragma unroll
      for (int j=0;j<TN;j++) acc[i][j]=0.f;

    for (int k0=0;k0<K;k0+=BK){
        const int gr = m0 + lrow;
        const int gc = n0 + lrow;
        if (VEC){
            float4 va = make_float4(0.f,0.f,0.f,0.f), vb = make_float4(0.f,0.f,0.f,0.f);
            if (gr < M) va = *reinterpret_cast<const float4*>(A + (size_t)gr*lda + k0 + lcol);
            if (gc < N) vb = *reinterpret_cast<const float4*>(B + (size_t)gc*ldb + k0 + lcol);
            As[lcol+0][lrow]=va.x; As[lcol+1][lrow]=va.y; As[lcol+2][lrow]=va.z; As[lcol+3][lrow]=va.w;
            Bs[lcol+0][lrow]=vb.x; Bs[lcol+1][lrow]=vb.y; Bs[lcol+2][lrow]=vb.z; Bs[lcol+3][lrow]=vb.w;
        } else {
            #pragma unroll
            for (int j=0;j<4;j++){
                int kk = k0 + lcol + j;
                float va = (gr<M && kk<K) ? A[(size_t)gr*lda + kk] : 0.f;
                float vb = (gc<N && kk<K) ? B[(size_t)gc*ldb + kk] : 0.f;
                As[lcol+j][lrow]=va;
                Bs[lcol+j][lrow]=vb;
            }
        }
        __syncthreads();
        #pragma unroll
        for (int k=0;k<BK;k++){
            float a[TM], b[TN];
            #pragma unroll
            for (int i=0;i<TM;i++) a[i] = As[k][ty*TM+i];
            #pragma unroll
            for (int j=0;j<TN;j++) b[j] = Bs[k][tx*TN+j];
            #pragma unroll
            for (int i=0;i<TM;i++)
              #pragma unroll
              for (int j=0;j<TN;j++) acc[i][j] = fmaf(a[i], b[j], acc[i][j]);
        }
        __syncthreads();
    }
    #pragma unroll
    for (int i=0;i<TM;i++){
        const int gr = m0 + ty*TM + i;
        if (gr >= M) continue;
        #pragma unroll
        for (int j=0;j<TN;j++){
            const int gc = n0 + tx*TN + j;
            if (gc < N) C[(size_t)gr*ldc + gc] = acc[i][j];
        }
    }
}

// GRU gate fusion: h = (1-z)*n + z*h, gate order (r,z,n); optional second gi operand.
__global__ __launch_bounds__(256) void gru_update(const float* __restrict__ gi,
                                                  const float* __restrict__ gi2,
                                                  const float* __restrict__ gh,
                                                  const float* __restrict__ bih,
                                                  const float* __restrict__ bhh,
                                                  float* __restrict__ h,
                                                  float* __restrict__ out2,
                                                  int R)
{
    int idx = blockIdx.x*256 + threadIdx.x;
    if (idx >= R*HHc) return;
    const int row = idx >> 10;
    const int i   = idx & (HHc-1);
    const size_t b3 = (size_t)row * H3c;
    float ir  = gi[b3 + i]          + bih[i];
    float iz  = gi[b3 + HHc + i]    + bih[HHc + i];
    float inn = gi[b3 + 2*HHc + i]  + bih[2*HHc + i];
    if (gi2){
        ir  += gi2[b3 + i];
        iz  += gi2[b3 + HHc + i];
        inn += gi2[b3 + 2*HHc + i];
    }
    const float hr = gh[b3 + i]         + bhh[i];
    const float hz = gh[b3 + HHc + i]   + bhh[HHc + i];
    const float hn = gh[b3 + 2*HHc + i] + bhh[2*HHc + i];
    const float r = sigmoidf_(ir + hr);
    const float z = sigmoidf_(iz + hz);
    const float n = tanhf(inn + r*hn);
    const float hnew = (1.f - z)*n + z*h[idx];
    h[idx] = hnew;
    if (out2) out2[idx] = hnew;
}

__global__ __launch_bounds__(256) void bias_tanh(float* __restrict__ x,
                                                 const float* __restrict__ b,
                                                 int total, int D)
{
    int idx = blockIdx.x*256 + threadIdx.x;
    if (idx >= total) return;
    x[idx] = tanhf(x[idx] + b[idx % D]);
}

// xb[s][ne*B+b][k] = target[(ne*S+s)][b][k]
__global__ __launch_bounds__(256) void rearrange_x(const float* __restrict__ t,
                                                   float* __restrict__ xb)
{
    int idx = blockIdx.x*256 + threadIdx.x;
    if (idx >= SNBc*INc) return;
    const int k = idx % INc;
    const int rowall = idx / INc;       // s*4096 + ne*256 + b
    const int s  = rowall >> 12;
    const int r  = rowall & 4095;
    const int ne = r >> 8;
    const int b  = r & 255;
    xb[idx] = t[(((size_t)(ne*SSc + s)*BBc + b)*INc) + k];
}

// hd_l[ne*B+b][h] = h0_dec[ne][l][b][h]
__global__ __launch_bounds__(256) void init_hd(const float* __restrict__ h0dec,
                                               float* __restrict__ hd0,
                                               float* __restrict__ hd1)
{
    int idx = blockIdx.x*256 + threadIdx.x;
    if (idx >= NEBc*HHc) return;
    const int hh = idx & (HHc-1);
    const int r  = idx >> 10;
    const int ne = r >> 8;
    const int b  = r & 255;
    hd0[idx] = h0dec[(((size_t)ne*2 + 0)*BBc + b)*HHc + hh];
    hd1[idx] = h0dec[(((size_t)ne*2 + 1)*BBc + b)*HHc + hh];
}

// Per-step: softmax over 61 logits per row (one wave per row) + scatter to output layout
__global__ __launch_bounds__(256) void softmax_out(const float* __restrict__ logits,
                                                   const float* __restrict__ ob,
                                                   float* __restrict__ out, int t)
{
    const int r    = blockIdx.x*4 + (threadIdx.x >> 6);
    const int lane = threadIdx.x & 63;
    float v = -1e30f;
    if (lane < INc) v = logits[(size_t)r*INc + lane] + ob[lane];
    float m = v;
    #pragma unroll
    for (int o=32;o>0;o>>=1) m = fmaxf(m, __shfl_xor(m, o));
    float e = (lane < INc) ? __expf(v - m) : 0.f;
    float s = e;
    #pragma unroll
    for (int o=32;o>0;o>>=1) s += __shfl_xor(s, o);
    if (lane < INc){
        const int ne = r >> 8, b = r & 255;
        out[((size_t)((ne*SSc + t)*BBc + b))*INc + lane] = e / s;
    }
}

// ---------------- host side ----------------

static void gemm(const float* A,int lda,const float* B,int ldb,float* C,int ldc,
                 int M,int N,int K,hipStream_t st)
{
    const bool al = ((lda&3)==0) && ((ldb&3)==0)
                 && ((((uintptr_t)A)&15)==0) && ((((uintptr_t)B)&15)==0);
    if (M>=1024 && N>=128 && al && (K&7)==0){
        dim3 g((N+127)/128,(M+127)/128);
        hipLaunchKernelGGL((gemm_nt<128,128,8,8,8,true>), g, dim3(256),0,st, A,lda,B,ldb,C,ldc,M,N,K);
    } else if (al && (K&15)==0){
        dim3 g((N+63)/64,(M+63)/64);
        hipLaunchKernelGGL((gemm_nt<64,64,16,4,4,true>), g, dim3(256),0,st, A,lda,B,ldb,C,ldc,M,N,K);
    } else {
        dim3 g((N+63)/64,(M+63)/64);
        hipLaunchKernelGGL((gemm_nt<64,64,16,4,4,false>), g, dim3(256),0,st, A,lda,B,ldb,C,ldc,M,N,K);
    }
}

extern "C" void kernel_launch(void* const* d_in, const int* in_sizes, int n_in,
                              void* d_out, int out_size, void* d_ws, size_t ws_size,
                              hipStream_t stream)
{
    const float* target = (const float*)d_in[0];
    const float* latent = (const float*)d_in[1];
    const float* h0     = (const float*)d_in[2];
    const float* h0_dec = (const float*)d_in[3];
    const float* c_wih0 = (const float*)d_in[4];
    const float* c_whh0 = (const float*)d_in[5];
    const float* c_bih0 = (const float*)d_in[6];
    const float* c_bhh0 = (const float*)d_in[7];
    const float* c_wih1 = (const float*)d_in[8];
    const float* c_whh1 = (const float*)d_in[9];
    const float* c_bih1 = (const float*)d_in[10];
    const float* c_bhh1 = (const float*)d_in[11];
    const float* ce_w   = (const float*)d_in[12];
    const float* ce_b   = (const float*)d_in[13];
    const float* d_wih0 = (const float*)d_in[14];
    const float* d_whh0 = (const float*)d_in[15];
    const float* d_bih0 = (const float*)d_in[16];
    const float* d_bhh0 = (const float*)d_in[17];
    const float* d_wih1 = (const float*)d_in[18];
    const float* d_whh1 = (const float*)d_in[19];
    const float* d_bih1 = (const float*)d_in[20];
    const float* d_bhh1 = (const float*)d_in[21];
    const float* o_w    = (const float*)d_in[22];
    const float* o_b    = (const float*)d_in[23];
    float* out = (float*)d_out;

    float* p = (float*)d_ws;
    auto alloc = [&](size_t n){ float* q = p; p += n; return q; };
    float* gi0c = alloc((size_t)BBc*H3c);       // conductor l0 input gates (loop-invariant)
    float* ghc  = alloc((size_t)BBc*H3c);
    float* gic  = alloc((size_t)BBc*H3c);
    float* h0c  = alloc((size_t)BBc*HHc);
    float* h1c  = alloc((size_t)BBc*HHc);
    float* cout = alloc((size_t)NEc*BBc*HHc);   // conductor outputs
    float* emb  = alloc((size_t)NEBc*LLc);
    float* giE  = alloc((size_t)NEBc*H3c);      // emb part of decoder l0 input gates (step-invariant)
    float* giD  = alloc((size_t)NEBc*H3c);
    float* ghD  = alloc((size_t)NEBc*H3c);
    float* hd0  = alloc((size_t)NEBc*HHc);
    float* hd1  = alloc((size_t)NEBc*HHc);
    float* xb   = alloc((size_t)SNBc*INc);      // target rearranged to [S, NE*B, IN]

    // ---- setup ----
    hipMemcpyAsync(h0c, h0,                (size_t)BBc*HHc*4, hipMemcpyDeviceToDevice, stream);
    hipMemcpyAsync(h1c, h0 + (size_t)BBc*HHc, (size_t)BBc*HHc*4, hipMemcpyDeviceToDevice, stream);
    hipLaunchKernelGGL(init_hd, dim3((NEBc*HHc+255)/256), dim3(256),0,stream, h0_dec, hd0, hd1);
    hipLaunchKernelGGL(rearrange_x, dim3((SNBc*INc+255)/256), dim3(256),0,stream, target, xb);
    // loop-invariant conductor l0 input gates
    gemm(latent, LLc, c_wih0, LLc, gi0c, H3c, BBc, H3c, LLc, stream);

    // ---- conductor: 16 sequential 2-layer GRU steps ----
    for (int s=0;s<NEc;s++){
        gemm(h0c, HHc, c_whh0, HHc, ghc, H3c, BBc, H3c, HHc, stream);
        hipLaunchKernelGGL(gru_update, dim3((BBc*HHc+255)/256), dim3(256),0,stream,
                           gi0c, (const float*)nullptr, ghc, c_bih0, c_bhh0, h0c, (float*)nullptr, BBc);
        gemm(h0c, HHc, c_wih1, HHc, gic, H3c, BBc, H3c, HHc, stream);
        gemm(h1c, HHc, c_whh1, HHc, ghc, H3c, BBc, H3c, HHc, stream);
        hipLaunchKernelGGL(gru_update, dim3((BBc*HHc+255)/256), dim3(256),0,stream,
                           gic, (const float*)nullptr, ghc, c_bih1, c_bhh1, h1c,
                           cout + (size_t)s*BBc*HHc, BBc);
    }

    // ---- embedding ----
    gemm(cout, HHc, ce_w, HHc, emb, LLc, NEBc, LLc, HHc, stream);
    hipLaunchKernelGGL(bias_tanh, dim3((NEBc*LLc+255)/256), dim3(256),0,stream, emb, ce_b, NEBc*LLc, LLc);

    // step-invariant part of decoder l0 input gates: emb @ Wemb^T (Wemb = d_wih0[:, 61:], ldb=573)
    gemm(emb, LLc, d_wih0 + INc, INc+LLc, giE, H3c, NEBc, H3c, LLc, stream);

    // ---- decoder: 16 sequential 2-layer GRU steps, batch 4096 ----
    for (int t=0;t<SSc;t++){
        // x_t part of l0 input gates (K=61)
        gemm(xb + (size_t)t*NEBc*INc, INc, d_wih0, INc+LLc, giD, H3c, NEBc, H3c, INc, stream);
        gemm(hd0, HHc, d_whh0, HHc, ghD, H3c, NEBc, H3c, HHc, stream);
        hipLaunchKernelGGL(gru_update, dim3((NEBc*HHc+255)/256), dim3(256),0,stream,
                           giD, giE, ghD, d_bih0, d_bhh0, hd0, (float*)nullptr, NEBc);
        gemm(hd0, HHc, d_wih1, HHc, giD, H3c, NEBc, H3c, HHc, stream);
        gemm(hd1, HHc, d_whh1, HHc, ghD, H3c, NEBc, H3c, HHc, stream);
        hipLaunchKernelGGL(gru_update, dim3((NEBc*HHc+255)/256), dim3(256),0,stream,
                           giD, (const float*)nullptr, ghD, d_bih1, d_bhh1, hd1, (float*)nullptr, NEBc);
        // fused output projection (reuse giD as logits buffer) + softmax + scatter
        gemm(hd1, HHc, o_w, HHc, giD, INc, NEBc, INc, HHc, stream);
        hipLaunchKernelGGL(softmax_out, dim3(NEBc/4), dim3(256),0,stream, giD, o_b, out, t);
    }
}

// Round 2
// 3656.282 us; speedup vs baseline: 6.1555x; 6.1555x over previous
//
#include <hip/hip_runtime.h>
#include <hip/hip_bf16.h>
#include <cstdint>
#include <cstddef>

#define NEc 16
#define SSc 16
#define BBc 256
#define INc 61
#define HHc 1024
#define LLc 512
#define H3c 3072
#define NEBc 4096   // NE*B
#define KXc 64      // x width padded 61->64

typedef __hip_bfloat16 bf16;
typedef __attribute__((ext_vector_type(8))) short bf16x8;   // 8 bf16 = 4 VGPR (MFMA A/B frag)
typedef __attribute__((ext_vector_type(4))) float f32x4;    // MFMA C/D frag
typedef __attribute__((ext_vector_type(4))) short s16x4;    // 4 bf16 packed store

__device__ __forceinline__ void gload16(const void* g, void* l){
    __builtin_amdgcn_global_load_lds((const __attribute__((address_space(1))) unsigned int*)g,
                                     (__attribute__((address_space(3))) unsigned int*)l, 16, 0, 0);
}

__device__ __forceinline__ float sigmoidf_(float x){ return 1.0f/(1.0f+__expf(-x)); }

// ---------------------------------------------------------------------------
// bf16 MFMA GEMM-NT: C[M,N] = A[M,K] @ B[N,K]^T, A/B bf16 (lda=ldb=K), C fp32.
// 128x128 (or 64x128 / 64x64) tile, BK=64, 4 waves, 16x16x32 MFMA.
// Staging: global_load_lds width 16, linear LDS dest; XOR swizzle
// (granule ^= row&7, bits 4-6 of the 128B row) applied to the *source*
// address and again on ds_read -> <=2-way bank conflict (free).
// gridDim.z selects (A0,B0,C0) or (A1,B1,C1) -> twin GEMMs in one launch.
// Requires: M%BM==0, N%BN==0, K%64==0, 16B-aligned pointers.
// ---------------------------------------------------------------------------
template<int BM,int BN>
__global__ __launch_bounds__(256)
void gemm_bf(const bf16* __restrict__ A0, const bf16* __restrict__ B0, float* __restrict__ C0,
             const bf16* __restrict__ A1, const bf16* __restrict__ B1, float* __restrict__ C1,
             int K, int ldc)
{
    constexpr int WAVES_M = (BM==128) ? 2 : 1;
    constexpr int WAVES_N = 4 / WAVES_M;
    constexpr int WM = BM / WAVES_M;
    constexpr int WN = BN / WAVES_N;
    constexpr int MR = WM / 16;
    constexpr int NR = WN / 16;
    constexpr int ASW = (BM*128)/4096;   // 16B sweeps per 256 threads
    constexpr int BSW = (BN*128)/4096;

    __shared__ char smem[(BM+BN)*128];
    char* sA = smem;
    char* sB = smem + BM*128;

    const bf16* A = A0; const bf16* Bm = B0; float* C = C0;
    if (blockIdx.z == 1){ A = A1; Bm = B1; C = C1; }

    const int tid  = threadIdx.x;
    const int lane = tid & 63;
    const int wave = tid >> 6;
    const int wm   = (WAVES_M==2) ? (wave>>1) : 0;
    const int wn   = (WAVES_M==2) ? (wave&1)  : wave;
    const int lr   = lane & 15;
    const int lk   = lane >> 4;
    const int m0   = blockIdx.y * BM;
    const int n0   = blockIdx.x * BN;

    f32x4 acc[MR][NR];
    #pragma unroll
    for (int mi=0;mi<MR;mi++)
      #pragma unroll
      for (int ni=0;ni<NR;ni++)
        #pragma unroll
        for (int j=0;j<4;j++) acc[mi][ni][j] = 0.f;

    for (int k0 = 0; k0 < K; k0 += 64){
        if (k0) __syncthreads();              // protect LDS from prior reads
        #pragma unroll
        for (int i=0;i<ASW;i++){
            const int o = i*4096 + tid*16;    // linear LDS byte offset
            const int u = o ^ (((o>>7)&7)<<4);// pre-swizzled source position
            gload16(A + (size_t)(m0 + (u>>7))*K + k0 + ((u&127)>>1), sA + o);
        }
        #pragma unroll
        for (int i=0;i<BSW;i++){
            const int o = i*4096 + tid*16;
            const int u = o ^ (((o>>7)&7)<<4);
            gload16(Bm + (size_t)(n0 + (u>>7))*K + k0 + ((u&127)>>1), sB + o);
        }
        __syncthreads();                      // compiler drains vmcnt(0) here

        #pragma unroll
        for (int ks=0;ks<2;ks++){
            bf16x8 av[MR], bv[NR];
            #pragma unroll
            for (int mi=0;mi<MR;mi++){
                const int r = wm*WM + mi*16 + lr;
                const int u = r*128 + ks*64 + lk*16;
                av[mi] = *(const bf16x8*)(sA + (u ^ ((r&7)<<4)));
            }
            #pragma unroll
            for (int ni=0;ni<NR;ni++){
                const int r = wn*WN + ni*16 + lr;
                const int u = r*128 + ks*64 + lk*16;
                bv[ni] = *(const bf16x8*)(sB + (u ^ ((r&7)<<4)));
            }
            #pragma unroll
            for (int mi=0;mi<MR;mi++)
              #pragma unroll
              for (int ni=0;ni<NR;ni++)
                acc[mi][ni] = __builtin_amdgcn_mfma_f32_16x16x32_bf16(av[mi], bv[ni], acc[mi][ni], 0,0,0);
        }
    }

    // C/D layout (m89): col = lane&15, row = (lane>>4)*4 + reg
    #pragma unroll
    for (int mi=0;mi<MR;mi++)
      #pragma unroll
      for (int ni=0;ni<NR;ni++)
        #pragma unroll
        for (int j=0;j<4;j++){
            const int r = m0 + wm*WM + mi*16 + lk*4 + j;
            const int c = n0 + wn*WN + ni*16 + lr;
            C[(size_t)r*ldc + c] = acc[mi][ni][j];
        }
}

// ---------------------------------------------------------------------------
// GRU gate fusion (float4): h = (1-z)*n + z*h; writes fp32 h + bf16 shadow.
// ---------------------------------------------------------------------------
__global__ __launch_bounds__(256)
void gru4(const float* __restrict__ gi, const float* __restrict__ gi2,
          const float* __restrict__ gh,
          const float* __restrict__ bih, const float* __restrict__ bhh,
          float* __restrict__ h, bf16* __restrict__ hb, bf16* __restrict__ out2, int R)
{
    const int idx = blockIdx.x*256 + threadIdx.x;      // quad index
    if (idx >= R*(HHc/4)) return;
    const int e   = idx*4;
    const int row = e >> 10;
    const int i   = e & (HHc-1);
    const size_t b3 = (size_t)row * H3c;

    f32x4 ir = *(const f32x4*)(gi + b3 + i)          + *(const f32x4*)(bih + i);
    f32x4 iz = *(const f32x4*)(gi + b3 + HHc + i)    + *(const f32x4*)(bih + HHc + i);
    f32x4 in_= *(const f32x4*)(gi + b3 + 2*HHc + i)  + *(const f32x4*)(bih + 2*HHc + i);
    if (gi2){
        ir  += *(const f32x4*)(gi2 + b3 + i);
        iz  += *(const f32x4*)(gi2 + b3 + HHc + i);
        in_ += *(const f32x4*)(gi2 + b3 + 2*HHc + i);
    }
    const f32x4 hr = *(const f32x4*)(gh + b3 + i)         + *(const f32x4*)(bhh + i);
    const f32x4 hz = *(const f32x4*)(gh + b3 + HHc + i)   + *(const f32x4*)(bhh + HHc + i);
    const f32x4 hn = *(const f32x4*)(gh + b3 + 2*HHc + i) + *(const f32x4*)(bhh + 2*HHc + i);
    f32x4 hv = *(const f32x4*)(h + e);

    union { s16x4 v; bf16 b[4]; } pk;
    #pragma unroll
    for (int j=0;j<4;j++){
        const float r = sigmoidf_(ir[j] + hr[j]);
        const float z = sigmoidf_(iz[j] + hz[j]);
        const float n = tanhf(in_[j] + r*hn[j]);
        const float hnew = (1.f - z)*n + z*hv[j];
        hv[j] = hnew;
        pk.b[j] = __float2bfloat16(hnew);
    }
    *(f32x4*)(h + e) = hv;
    *(s16x4*)(hb + e) = pk.v;
    if (out2) *(s16x4*)(out2 + e) = pk.v;
}

// ---------------------------------------------------------------------------
// conversions / packing
// ---------------------------------------------------------------------------
__global__ __launch_bounds__(256) void cvt_bf16_k(const float* __restrict__ in, bf16* __restrict__ out, int n4){
    const int i = blockIdx.x*256 + threadIdx.x;
    if (i >= n4) return;
    const f32x4 v = *(const f32x4*)(in + (size_t)i*4);
    union { s16x4 s; bf16 b[4]; } u;
    #pragma unroll
    for (int j=0;j<4;j++) u.b[j] = __float2bfloat16(v[j]);
    *(s16x4*)(out + (size_t)i*4) = u.s;
}

// d_wih0 [3072][573] -> wx [3072][64] (cols 0..60, zero-pad) + we [3072][512]
__global__ __launch_bounds__(256) void split_wih0(const float* __restrict__ w,
                                                  bf16* __restrict__ wx, bf16* __restrict__ we){
    const int idx = blockIdx.x*256 + threadIdx.x;
    if (idx >= 3072*576) return;
    const int r = idx / 576, c = idx % 576;
    if (c < KXc) wx[r*KXc + c] = __float2bfloat16(c < INc ? w[(size_t)r*(INc+LLc) + c] : 0.f);
    else         we[r*LLc + (c-KXc)] = __float2bfloat16(w[(size_t)r*(INc+LLc) + INc + (c-KXc)]);
}

// o_w [61][1024] -> owb [64][1024] zero-padded rows
__global__ __launch_bounds__(256) void pad_ow(const float* __restrict__ w, bf16* __restrict__ o){
    const int idx = blockIdx.x*256 + threadIdx.x;
    if (idx >= KXc*HHc) return;
    const int r = idx >> 10;
    o[idx] = __float2bfloat16(r < INc ? w[(size_t)r*HHc + (idx & (HHc-1))] : 0.f);
}

// target [NE*S][B][61] -> xb bf16 [S][NE*B][64] zero-padded
__global__ __launch_bounds__(256) void build_xb(const float* __restrict__ t, bf16* __restrict__ xb){
    const int idx = blockIdx.x*256 + threadIdx.x;
    if (idx >= SSc*NEBc*KXc) return;
    const int c  = idx & 63;
    const int rr = idx >> 6;
    const int s  = rr >> 12;
    const int r  = rr & 4095;
    const int ne = r >> 8;
    const int b  = r & 255;
    const float v = (c < INc) ? t[(((size_t)(ne*SSc + s)*BBc + b)*INc) + c] : 0.f;
    xb[idx] = __float2bfloat16(v);
}

// h0 [2][256][1024] -> h0c/h1c fp32 + bf16 shadows (4-wide)
__global__ __launch_bounds__(256) void init_hc(const float* __restrict__ h0,
                                               float* __restrict__ h0c, float* __restrict__ h1c,
                                               bf16* __restrict__ h0cb, bf16* __restrict__ h1cb){
    const int i = blockIdx.x*256 + threadIdx.x;
    if (i >= (BBc*HHc)/4) return;
    const int e = i*4;
    f32x4 a = *(const f32x4*)(h0 + e);
    f32x4 b = *(const f32x4*)(h0 + BBc*HHc + e);
    union { s16x4 v; bf16 q[4]; } ua, ub;
    #pragma unroll
    for (int j=0;j<4;j++){ ua.q[j]=__float2bfloat16(a[j]); ub.q[j]=__float2bfloat16(b[j]); }
    *(f32x4*)(h0c + e) = a; *(f32x4*)(h1c + e) = b;
    *(s16x4*)(h0cb + e) = ua.v; *(s16x4*)(h1cb + e) = ub.v;
}

// h0_dec [NE][2][256][1024] -> hd0/hd1 [NE*B][H] fp32 + bf16 (4-wide)
__global__ __launch_bounds__(256) void init_hd(const float* __restrict__ hd,
                                               float* __restrict__ hd0, float* __restrict__ hd1,
                                               bf16* __restrict__ hd0b, bf16* __restrict__ hd1b){
    const int i = blockIdx.x*256 + threadIdx.x;
    if (i >= (NEBc*HHc)/4) return;
    const int e  = i*4;
    const int hh = e & (HHc-1);
    const int r  = e >> 10;
    const int ne = r >> 8;
    const int b  = r & 255;
    f32x4 a = *(const f32x4*)(hd + (((size_t)ne*2 + 0)*BBc + b)*HHc + hh);
    f32x4 c = *(const f32x4*)(hd + (((size_t)ne*2 + 1)*BBc + b)*HHc + hh);
    union { s16x4 v; bf16 q[4]; } ua, uc;
    #pragma unroll
    for (int j=0;j<4;j++){ ua.q[j]=__float2bfloat16(a[j]); uc.q[j]=__float2bfloat16(c[j]); }
    *(f32x4*)(hd0 + e) = a; *(f32x4*)(hd1 + e) = c;
    *(s16x4*)(hd0b + e) = ua.v; *(s16x4*)(hd1b + e) = uc.v;
}

// emb fp32 -> tanh(emb+b) -> bf16 (4-wide)
__global__ __launch_bounds__(256) void bias_tanh4(const float* __restrict__ in,
                                                  const float* __restrict__ b, bf16* __restrict__ out){
    const int i = blockIdx.x*256 + threadIdx.x;
    if (i >= (NEBc*LLc)/4) return;
    const int e = i*4;
    const int c = e & (LLc-1);
    f32x4 v = *(const f32x4*)(in + e);
    f32x4 bb = *(const f32x4*)(b + c);
    union { s16x4 s; bf16 q[4]; } u;
    #pragma unroll
    for (int j=0;j<4;j++) u.q[j] = __float2bfloat16(tanhf(v[j] + bb[j]));
    *(s16x4*)(out + e) = u.s;
}

// softmax over 61 logits (stride 64) per row, one wave per row, scatter to output
__global__ __launch_bounds__(256) void softmax_out(const float* __restrict__ logits,
                                                   const float* __restrict__ ob,
                                                   float* __restrict__ out, int t)
{
    const int r    = blockIdx.x*4 + (threadIdx.x >> 6);
    const int lane = threadIdx.x & 63;
    float v = -1e30f;
    if (lane < INc) v = logits[(size_t)r*KXc + lane] + ob[lane];
    float m = v;
    #pragma unroll
    for (int o=32;o>0;o>>=1) m = fmaxf(m, __shfl_xor(m, o));
    float e = (lane < INc) ? __expf(v - m) : 0.f;
    float s = e;
    #pragma unroll
    for (int o=32;o>0;o>>=1) s += __shfl_xor(s, o);
    if (lane < INc){
        const int ne = r >> 8, b = r & 255;
        out[((size_t)((ne*SSc + t)*BBc + b))*INc + lane] = e / s;
    }
}

// ---------------- host side ----------------

extern "C" void kernel_launch(void* const* d_in, const int* in_sizes, int n_in,
                              void* d_out, int out_size, void* d_ws, size_t ws_size,
                              hipStream_t stream)
{
    const float* target = (const float*)d_in[0];
    const float* latent = (const float*)d_in[1];
    const float* h0     = (const float*)d_in[2];
    const float* h0_dec = (const float*)d_in[3];
    const float* c_wih0 = (const float*)d_in[4];
    const float* c_whh0 = (const float*)d_in[5];
    const float* c_bih0 = (const float*)d_in[6];
    const float* c_bhh0 = (const float*)d_in[7];
    const float* c_wih1 = (const float*)d_in[8];
    const float* c_whh1 = (const float*)d_in[9];
    const float* c_bih1 = (const float*)d_in[10];
    const float* c_bhh1 = (const float*)d_in[11];
    const float* ce_w   = (const float*)d_in[12];
    const float* ce_b   = (const float*)d_in[13];
    const float* d_wih0 = (const float*)d_in[14];
    const float* d_whh0 = (const float*)d_in[15];
    const float* d_bih0 = (const float*)d_in[16];
    const float* d_bhh0 = (const float*)d_in[17];
    const float* d_wih1 = (const float*)d_in[18];
    const float* d_whh1 = (const float*)d_in[19];
    const float* d_bih1 = (const float*)d_in[20];
    const float* d_bhh1 = (const float*)d_in[21];
    const float* o_w    = (const float*)d_in[22];
    const float* o_b    = (const float*)d_in[23];
    float* out = (float*)d_out;

    // ---- workspace layout (~259 MB) ----
    float* fb = (float*)d_ws;
    float* giD = fb;                          // 4096x3072
    float* ghD = giD + (size_t)NEBc*H3c;      // 4096x3072
    float* giE = ghD + (size_t)NEBc*H3c;      // 4096x3072
    float* hd0 = giE + (size_t)NEBc*H3c;      // 4096x1024
    float* hd1 = hd0 + (size_t)NEBc*HHc;
    float* logits = hd1 + (size_t)NEBc*HHc;   // 4096x64
    bf16* sb   = (bf16*)(logits + (size_t)NEBc*KXc);
    bf16* embb = sb;                                  bf16* xb   = embb + (size_t)NEBc*LLc;
    bf16* hd0b = xb + (size_t)SSc*NEBc*KXc;           bf16* hd1b = hd0b + (size_t)NEBc*HHc;
    bf16* cw0b = hd1b + (size_t)NEBc*HHc;             // 3072x512
    bf16* cu0b = cw0b + (size_t)H3c*LLc;              // 3072x1024
    bf16* cw1b = cu0b + (size_t)H3c*HHc;
    bf16* cu1b = cw1b + (size_t)H3c*HHc;
    bf16* cewb = cu1b + (size_t)H3c*HHc;              // 512x1024
    bf16* wxb  = cewb + (size_t)LLc*HHc;              // 3072x64
    bf16* webb = wxb + (size_t)H3c*KXc;               // 3072x512
    bf16* du0b = webb + (size_t)H3c*LLc;
    bf16* dw1b = du0b + (size_t)H3c*HHc;
    bf16* du1b = dw1b + (size_t)H3c*HHc;
    bf16* owb  = du1b + (size_t)H3c*HHc;              // 64x1024
    // aliases: conductor fp32 scratch lives inside giD/ghD (dead until decoder);
    // conductor bf16 scratch inside giE (dead until giE GEMM, which runs after last use)
    float* gi0c = giD;
    float* ghc  = gi0c + (size_t)BBc*H3c;
    float* gic  = ghc  + (size_t)BBc*H3c;
    float* h0c  = gic  + (size_t)BBc*H3c;
    float* h1c  = h0c  + (size_t)BBc*HHc;
    float* emb  = ghD;                                // 4096x512, dead after bias_tanh4
    bf16* coutb = (bf16*)giE;                         // 4096x1024, dead after ce GEMM
    bf16* h0cb  = coutb + (size_t)NEBc*HHc;
    bf16* h1cb  = h0cb + (size_t)BBc*HHc;
    bf16* latb  = h1cb + (size_t)BBc*HHc;

    auto cvt = [&](const float* in, bf16* o, size_t n){
        hipLaunchKernelGGL(cvt_bf16_k, dim3((unsigned)((n/4+255)/256)), dim3(256),0,stream, in,o,(int)(n/4));
    };

    // ---- setup: weight + activation conversions ----
    cvt(c_wih0, cw0b, (size_t)H3c*LLc);
    cvt(c_whh0, cu0b, (size_t)H3c*HHc);
    cvt(c_wih1, cw1b, (size_t)H3c*HHc);
    cvt(c_whh1, cu1b, (size_t)H3c*HHc);
    cvt(ce_w,   cewb, (size_t)LLc*HHc);
    cvt(d_whh0, du0b, (size_t)H3c*HHc);
    cvt(d_wih1, dw1b, (size_t)H3c*HHc);
    cvt(d_whh1, du1b, (size_t)H3c*HHc);
    cvt(latent, latb, (size_t)BBc*LLc);
    hipLaunchKernelGGL(split_wih0, dim3((3072*576+255)/256), dim3(256),0,stream, d_wih0, wxb, webb);
    hipLaunchKernelGGL(pad_ow, dim3((KXc*HHc)/256), dim3(256),0,stream, o_w, owb);
    hipLaunchKernelGGL(build_xb, dim3((SSc*NEBc*KXc)/256), dim3(256),0,stream, target, xb);
    hipLaunchKernelGGL(init_hc, dim3((BBc*HHc/4)/256), dim3(256),0,stream, h0, h0c, h1c, h0cb, h1cb);
    hipLaunchKernelGGL(init_hd, dim3((NEBc*HHc/4)/256), dim3(256),0,stream, h0_dec, hd0, hd1, hd0b, hd1b);

    // conductor l0 input gates (loop-invariant): gi0c = latent @ c_wih0^T
    hipLaunchKernelGGL((gemm_bf<64,128>), dim3(H3c/128, BBc/64, 1), dim3(256),0,stream,
                       latb, cw0b, gi0c, latb, cw0b, gi0c, LLc, H3c);

    // ---- conductor: 16 sequential 2-layer GRU steps (M=256) ----
    for (int s=0;s<NEc;s++){
        hipLaunchKernelGGL((gemm_bf<64,128>), dim3(H3c/128, BBc/64, 1), dim3(256),0,stream,
                           h0cb, cu0b, ghc, h0cb, cu0b, ghc, HHc, H3c);
        hipLaunchKernelGGL(gru4, dim3((BBc*HHc/4)/256), dim3(256),0,stream,
                           gi0c, (const float*)nullptr, ghc, c_bih0, c_bhh0, h0c, h0cb, (bf16*)nullptr, BBc);
        hipLaunchKernelGGL((gemm_bf<64,128>), dim3(H3c/128, BBc/64, 2), dim3(256),0,stream,
                           h0cb, cw1b, gic, h1cb, cu1b, ghc, HHc, H3c);
        hipLaunchKernelGGL(gru4, dim3((BBc*HHc/4)/256), dim3(256),0,stream,
                           gic, (const float*)nullptr, ghc, c_bih1, c_bhh1, h1c, h1cb,
                           coutb + (size_t)s*BBc*HHc, BBc);
    }

    // ---- embedding: emb = tanh(cout @ ce_w^T + b) ----
    hipLaunchKernelGGL((gemm_bf<128,128>), dim3(LLc/128, NEBc/128, 1), dim3(256),0,stream,
                       coutb, cewb, emb, coutb, cewb, emb, HHc, LLc);
    hipLaunchKernelGGL(bias_tanh4, dim3((NEBc*LLc/4)/256), dim3(256),0,stream, emb, ce_b, embb);

    // step-invariant decoder l0 gates from emb: giE = emb @ We^T  (overwrites coutb alias - cout is dead)
    hipLaunchKernelGGL((gemm_bf<128,128>), dim3(H3c/128, NEBc/128, 1), dim3(256),0,stream,
                       embb, webb, giE, embb, webb, giE, LLc, H3c);

    // ---- decoder: 16 sequential 2-layer GRU steps (M=4096) ----
    for (int t=0;t<SSc;t++){
        hipLaunchKernelGGL((gemm_bf<128,128>), dim3(H3c/128, NEBc/128, 1), dim3(256),0,stream,
                           xb + (size_t)t*NEBc*KXc, wxb, giD,
                           xb + (size_t)t*NEBc*KXc, wxb, giD, KXc, H3c);
        hipLaunchKernelGGL((gemm_bf<128,128>), dim3(H3c/128, NEBc/128, 1), dim3(256),0,stream,
                           hd0b, du0b, ghD, hd0b, du0b, ghD, HHc, H3c);
        hipLaunchKernelGGL(gru4, dim3((NEBc*HHc/4)/256), dim3(256),0,stream,
                           giD, giE, ghD, d_bih0, d_bhh0, hd0, hd0b, (bf16*)nullptr, NEBc);
        hipLaunchKernelGGL((gemm_bf<128,128>), dim3(H3c/128, NEBc/128, 2), dim3(256),0,stream,
                           hd0b, dw1b, giD, hd1b, du1b, ghD, HHc, H3c);
        hipLaunchKernelGGL(gru4, dim3((NEBc*HHc/4)/256), dim3(256),0,stream,
                           giD, (const float*)nullptr, ghD, d_bih1, d_bhh1, hd1, hd1b, (bf16*)nullptr, NEBc);
        hipLaunchKernelGGL((gemm_bf<64,64>), dim3(KXc/64, NEBc/64, 1), dim3(256),0,stream,
                           hd1b, owb, logits, hd1b, owb, logits, HHc, KXc);
        hipLaunchKernelGGL(softmax_out, dim3(NEBc/4), dim3(256),0,stream, logits, o_b, out, t);
    }
}